// Round 6
// baseline (149.078 us; speedup 1.0000x reference)
//
#include <hip/hip_runtime.h>

// Token reorderer: stable counting sort by expert id (64 experts).
// Outputs (float32, concatenated): [0,N) sorted scores, [N,2N) permutation,
// [2N,2N+64) per-expert counts.
//
// R13 = R12 with scores removed from the LDS path.
//  - sdat holds only packed keys (i<<6)|e (4 B): LDS 38->21.3 KB ->
//    7 blocks/CU; pass-2 scatter is ds_write_b32 (half the conflict
//    cycles of uint2); phase D gathers scores[i] straight from global
//    (tile region is 16 KB, 64B-line reuse 16x, L2-resident -> HBM
//    traffic unchanged).
//  - pass 1 no longer loads scores at all (-16 VGPR, -16 VMEM issues).
//  - idx staging aliases sdat exactly (16 KB).
//  - hist/scan unchanged from R12 (TILE 4096, [tile][64] countsT).

#define TILE 4096          // elements per tile (256 threads, 4 waves)
#define WCH  1024          // elements per wave
#define RND  16            // rounds of 64 per wave

__device__ __forceinline__ unsigned long long match_mask(
    unsigned key,
    unsigned long long b0, unsigned long long b1, unsigned long long b2,
    unsigned long long b3, unsigned long long b4, unsigned long long b5,
    unsigned long long am) {
  unsigned long long m = am;
  m &= (key & 1u)  ? b0 : ~b0;
  m &= (key & 2u)  ? b1 : ~b1;
  m &= (key & 4u)  ? b2 : ~b2;
  m &= (key & 8u)  ? b3 : ~b3;
  m &= (key & 16u) ? b4 : ~b4;
  m &= (key & 32u) ? b5 : ~b5;
  return m;
}

// Kernel 1: per-tile expert histogram via ballots (no atomics).
// countsT layout: [tile][64] -> one coalesced 256 B write per block.
__global__ __launch_bounds__(256) void hist_kernel(
    const int* __restrict__ idx, unsigned* __restrict__ countsT,
    int N, int nb) {
  __shared__ unsigned h[4][64];
  const int wave = threadIdx.x >> 6;
  const int lane = threadIdx.x & 63;

  long long base = (long long)blockIdx.x * TILE;
  long long rem = (long long)N - base;
  unsigned cnt = 0;

  if (rem >= TILE) {
    const int4* v = (const int4*)(idx + base);
    unsigned es[16];
    #pragma unroll
    for (int k = 0; k < 4; ++k) {
      int4 x = v[threadIdx.x + k * 256];
      es[k * 4 + 0] = ((unsigned)x.x) & 63u;
      es[k * 4 + 1] = ((unsigned)x.y) & 63u;
      es[k * 4 + 2] = ((unsigned)x.z) & 63u;
      es[k * 4 + 3] = ((unsigned)x.w) & 63u;
    }
    #pragma unroll
    for (int r = 0; r < 16; ++r) {
      unsigned e = es[r];
      unsigned long long b0 = __ballot(e & 1u);
      unsigned long long b1 = __ballot(e & 2u);
      unsigned long long b2 = __ballot(e & 4u);
      unsigned long long b3 = __ballot(e & 8u);
      unsigned long long b4 = __ballot(e & 16u);
      unsigned long long b5 = __ballot(e & 32u);
      cnt += (unsigned)__popcll(
          match_mask((unsigned)lane, b0, b1, b2, b3, b4, b5, ~0ull));
    }
  } else {
    long long wstart = base + (long long)wave * WCH;
    for (int r = 0; r < RND; ++r) {
      long long i = wstart + (long long)r * 64 + lane;
      bool valid = i < (long long)N;
      unsigned long long am = __ballot(valid ? 1 : 0);
      unsigned e = valid ? (((unsigned)idx[i]) & 63u) : 0u;
      unsigned long long b0 = __ballot(e & 1u);
      unsigned long long b1 = __ballot(e & 2u);
      unsigned long long b2 = __ballot(e & 4u);
      unsigned long long b3 = __ballot(e & 8u);
      unsigned long long b4 = __ballot(e & 16u);
      unsigned long long b5 = __ballot(e & 32u);
      cnt += (unsigned)__popcll(
          match_mask((unsigned)lane, b0, b1, b2, b3, b4, b5, am));
    }
  }

  h[wave][lane] = cnt;
  __syncthreads();
  if (threadIdx.x < 64) {
    countsT[(size_t)blockIdx.x * 64 + threadIdx.x] =
        h[0][threadIdx.x] + h[1][threadIdx.x] + h[2][threadIdx.x] + h[3][threadIdx.x];
  }
}

// Kernel 2: per-expert exclusive scan over tiles, chunked through LDS.
// countsT[t*64+e]; strided accesses are L2-resident (512 KB total).
// nb=2048 -> exactly one chunk.
__global__ __launch_bounds__(256) void scan_kernel(
    unsigned* __restrict__ countsT, unsigned* __restrict__ totals,
    float* __restrict__ out_counts, int nb) {
  const int e = blockIdx.x;   // 0..63
  const int t = threadIdx.x;  // 0..255
  const int wave = t >> 6;
  const int lane = t & 63;

  __shared__ unsigned buf[2048];
  __shared__ unsigned wsum[4];

  unsigned carry = 0;
  for (int c = 0; c < nb; c += 2048) {
    int m = nb - c; if (m > 2048) m = 2048;
    for (int j = t; j < 2048; j += 256)
      buf[j] = (j < m) ? countsT[(size_t)(c + j) * 64 + e] : 0u;
    __syncthreads();
    unsigned v[8]; unsigned s = 0;
    #pragma unroll
    for (int k = 0; k < 8; ++k) { v[k] = buf[t * 8 + k]; s += v[k]; }
    unsigned inc = s;
    #pragma unroll
    for (int d = 1; d < 64; d <<= 1) {
      unsigned nv = __shfl_up(inc, d, 64);
      if (lane >= d) inc += nv;
    }
    if (lane == 63) wsum[wave] = inc;
    __syncthreads();
    unsigned woff = 0;
    for (int w = 0; w < wave; ++w) woff += wsum[w];
    unsigned btot = wsum[0] + wsum[1] + wsum[2] + wsum[3];
    unsigned run = carry + woff + (inc - s);
    #pragma unroll
    for (int k = 0; k < 8; ++k) { buf[t * 8 + k] = run; run += v[k]; }
    __syncthreads();
    for (int j = t; j < 2048; j += 256)
      if (j < m) countsT[(size_t)(c + j) * 64 + e] = buf[j];
    carry += btot;
    __syncthreads();
  }
  if (t == 0) {
    totals[e] = carry;
    out_counts[e] = (float)carry;  // output 2
  }
}

// Kernel 3: LDS-staged ballot sort (keys only), leader-publish counts,
// coalesced key write-out + L2-gathered score write-out.
__global__ __launch_bounds__(256, 7) void scatter_kernel(
    const int* __restrict__ idx, const float* __restrict__ scores,
    const unsigned* __restrict__ baseT, const unsigned* __restrict__ totals,
    float* __restrict__ out_scores, float* __restrict__ out_idx,
    int N, int nb) {
  // 16-byte aligned: accessed via int4/uint4 casts (ds_*_b128).
  __shared__ __align__(16) unsigned sdat[TILE];           // 16 KB; aliases idx staging
  __shared__ __align__(16) unsigned char tmpb[4][64][RND];// 4 KB leader-publish transpose
  __shared__ unsigned shc[4][64];                         // per-wave per-expert totals
  __shared__ unsigned gdest[64];                          // global dest = gdest[e] + lds_pos

  const int t = threadIdx.x;
  const int wave = t >> 6;
  const int lane = t & 63;
  const unsigned long long lt = (1ull << lane) - 1ull;

  const long long base = (long long)blockIdx.x * TILE;
  const long long start = base + (long long)wave * WCH;
  const bool fullt = (base + TILE) <= (long long)N;

  // hoisted global loads (consumed at table-calc time)
  const unsigned tot = totals[lane];
  const unsigned gb0 = baseT[(size_t)blockIdx.x * 64 + lane];  // coalesced

  unsigned e_pk[4] = {0, 0, 0, 0};
  unsigned r_pk[4] = {0, 0, 0, 0};
  unsigned c_pk[4];
  unsigned wtotal = 0;

  if (fullt) {
    // ---- Stage: idx -> LDS via b128 (only global loads in pass 1) ----
    {
      const int4* gi = (const int4*)(idx + base);
      int4 a0 = gi[t];
      int4 a1 = gi[t + 256];
      int4 a2 = gi[t + 512];
      int4 a3 = gi[t + 768];
      ((int4*)sdat)[t] = a0;
      ((int4*)sdat)[t + 256] = a1;
      ((int4*)sdat)[t + 512] = a2;
      ((int4*)sdat)[t + 768] = a3;
    }
    // zero my tmp row (same-wave DS ordering vs publishes)
    *(uint4*)(&tmpb[wave][lane][0]) = make_uint4(0u, 0u, 0u, 0u);
    __syncthreads();

    // ---- Pass 1: ballots from LDS; leader publishes per-round count ----
    #pragma unroll
    for (int r = 0; r < RND; ++r) {
      unsigned e = sdat[wave * WCH + r * 64 + lane] & 63u;
      unsigned long long b0 = __ballot(e & 1u);
      unsigned long long b1 = __ballot(e & 2u);
      unsigned long long b2 = __ballot(e & 4u);
      unsigned long long b3 = __ballot(e & 8u);
      unsigned long long b4 = __ballot(e & 16u);
      unsigned long long b5 = __ballot(e & 32u);
      unsigned long long ms = match_mask(e, b0, b1, b2, b3, b4, b5, ~0ull);
      unsigned rank = (unsigned)__popcll(ms & lt);
      unsigned rcnt = (unsigned)__popcll(ms);
      if (rank == 0) tmpb[wave][e][r] = (unsigned char)rcnt;
      const int q = r >> 2, sh = (r & 3) * 8;
      e_pk[q] |= e << sh;
      r_pk[q] |= rank << sh;
    }
    uint4 cw = *(const uint4*)(&tmpb[wave][lane][0]);  // after publishes (in-order)
    c_pk[0] = cw.x; c_pk[1] = cw.y; c_pk[2] = cw.z; c_pk[3] = cw.w;
  } else {
    for (int j = t; j < TILE; j += 256) sdat[j] = 0xFFFFFFFFu;
    *(uint4*)(&tmpb[wave][lane][0]) = make_uint4(0u, 0u, 0u, 0u);
    __syncthreads();
    unsigned epk_local[RND];
    for (int r = 0; r < RND; ++r) {
      long long i = start + (long long)r * 64 + lane;
      bool valid = i < (long long)N;
      unsigned long long am = __ballot(valid ? 1 : 0);
      unsigned e = valid ? (((unsigned)idx[i]) & 63u) : 0u;
      unsigned long long b0 = __ballot(e & 1u);
      unsigned long long b1 = __ballot(e & 2u);
      unsigned long long b2 = __ballot(e & 4u);
      unsigned long long b3 = __ballot(e & 8u);
      unsigned long long b4 = __ballot(e & 16u);
      unsigned long long b5 = __ballot(e & 32u);
      unsigned long long ms = match_mask(e, b0, b1, b2, b3, b4, b5, am);
      unsigned rank = (unsigned)__popcll(ms & lt);
      unsigned rcnt = (unsigned)__popcll(ms);
      if (valid && rank == 0) tmpb[wave][e][r] = (unsigned char)rcnt;
      const int q = r >> 2, sh = (r & 3) * 8;
      e_pk[q] |= e << sh;
      r_pk[q] |= rank << sh;
      (void)epk_local;
    }
    uint4 cw = *(const uint4*)(&tmpb[wave][lane][0]);
    c_pk[0] = cw.x; c_pk[1] = cw.y; c_pk[2] = cw.z; c_pk[3] = cw.w;
  }

  // wave total for expert==lane = byte-sum of c_pk (SIMD-in-register)
  {
    unsigned acc = 0;
    #pragma unroll
    for (int q = 0; q < 4; ++q)
      acc += (c_pk[q] & 0x00FF00FFu) + ((c_pk[q] >> 8) & 0x00FF00FFu);
    wtotal = (acc & 0xFFFFu) + (acc >> 16);
  }

  shc[wave][lane] = wtotal;
  __syncthreads();

  // ---- Block-level geometry for expert == lane ----
  unsigned c0 = shc[0][lane], c1 = shc[1][lane];
  unsigned c2 = shc[2][lane], c3 = shc[3][lane];
  unsigned bt = c0 + c1 + c2 + c3;          // block total for this expert
  unsigned wpre = 0;                        // waves before me, same expert
  if (wave > 0) wpre += c0;
  if (wave > 1) wpre += c1;
  if (wave > 2) wpre += c2;

  // exclusive scan of block totals over experts -> block-grouped LDS start
  unsigned s = bt;
  #pragma unroll
  for (int d = 1; d < 64; d <<= 1) {
    unsigned nv = __shfl_up(s, d, 64);
    if (lane >= d) s += nv;
  }
  unsigned bstart = s - bt;
  unsigned wbase = bstart + wpre;           // this wave's start for expert==lane

  // per-round cursors (register prefix)
  unsigned cur[RND];
  {
    unsigned acc = wbase;
    #pragma unroll
    for (int r = 0; r < RND; ++r) {
      cur[r] = acc;
      acc += (c_pk[r >> 2] >> ((r & 3) * 8)) & 0xffu;
    }
  }

  // global dest table (identical in all waves; wave 0 writes)
  if (wave == 0) {
    unsigned s2 = tot;
    #pragma unroll
    for (int d = 1; d < 64; d <<= 1) {
      unsigned nv = __shfl_up(s2, d, 64);
      if (lane >= d) s2 += nv;
    }
    unsigned estart = s2 - tot;             // global start of expert==lane
    gdest[lane] = estart + gb0 - bstart;    // u32 wraparound ok
  }

  // ---- Pass 2: scatter packed keys into block-grouped LDS (b32) ----
  if (fullt) {
    #pragma unroll
    for (int r = 0; r < RND; ++r) {
      unsigned i32 = (unsigned)start + r * 64 + lane;
      const int q = r >> 2, sh = (r & 3) * 8;
      unsigned e    = (e_pk[q] >> sh) & 0xffu;
      unsigned rank = (r_pk[q] >> sh) & 0xffu;
      unsigned pos = (unsigned)__shfl((int)cur[r], (int)e, 64) + rank;
      sdat[pos] = (i32 << 6) | e;
    }
  } else {
    for (int r = 0; r < RND; ++r) {
      long long i = start + (long long)r * 64 + lane;
      bool valid = i < (long long)N;
      const int q = r >> 2, sh = (r & 3) * 8;
      unsigned e    = (e_pk[q] >> sh) & 0xffu;
      unsigned rank = (r_pk[q] >> sh) & 0xffu;
      unsigned pos = (unsigned)__shfl((int)cur[r], (int)e, 64) + rank;
      if (valid) sdat[pos] = (((unsigned)i) << 6) | e;
    }
  }
  __syncthreads();

  // ---- Phase D: keys from LDS; scores gathered from global (L2-hot) ----
  if (fullt) {
    unsigned vv[TILE / 256];
    #pragma unroll
    for (int k = 0; k < TILE / 256; ++k) vv[k] = sdat[t + k * 256];
    float sc[TILE / 256];
    #pragma unroll
    for (int k = 0; k < TILE / 256; ++k) sc[k] = scores[vv[k] >> 6];
    #pragma unroll
    for (int k = 0; k < TILE / 256; ++k) {
      int j = t + k * 256;
      unsigned v = vv[k];
      unsigned d = gdest[v & 63u] + (unsigned)j;
      out_scores[d] = sc[k];
      out_idx[d] = (float)(v >> 6);
    }
  } else {
    for (int j = t; j < TILE; j += 256) {
      unsigned v = sdat[j];
      if (v == 0xFFFFFFFFu) continue;
      unsigned d = gdest[v & 63u] + (unsigned)j;
      out_scores[d] = scores[v >> 6];
      out_idx[d] = (float)(v >> 6);
    }
  }
}

extern "C" void kernel_launch(void* const* d_in, const int* in_sizes, int n_in,
                              void* d_out, int out_size, void* d_ws, size_t ws_size,
                              hipStream_t stream) {
  const float* scores = (const float*)d_in[0];
  const int* idx = (const int*)d_in[1];
  int N = in_sizes[0];  // 8388608

  float* out_scores = (float*)d_out;
  float* out_idx = out_scores + N;
  float* out_counts = out_idx + N;

  int nb = (N + TILE - 1) / TILE;                 // 2048
  unsigned* countsT = (unsigned*)d_ws;            // [nb][64], scanned in place
  unsigned* totals = countsT + (size_t)nb * 64;   // [64]

  hist_kernel<<<nb, 256, 0, stream>>>(idx, countsT, N, nb);
  scan_kernel<<<64, 256, 0, stream>>>(countsT, totals, out_counts, nb);
  scatter_kernel<<<nb, 256, 0, stream>>>(idx, scores, countsT, totals,
                                         out_scores, out_idx, N, nb);
}

// Round 7
// 138.911 us; speedup vs baseline: 1.0732x; 1.0732x over previous
//
#include <hip/hip_runtime.h>

// Token reorderer: stable counting sort by expert id (64 experts).
// Outputs (float32, concatenated): [0,N) sorted scores, [N,2N) permutation,
// [2N,2N+64) per-expert counts.
//
// R14 = R12 structure scaled to 512 threads / TILE 8192.
//  - R13's global score gather REVERTED (random-within-tile gather = 64
//    L2 transactions per wave-load; transaction-bound, -63% regression).
//    Scores go back through LDS as uint2 alongside the key.
//  - Per-wave ballot work unchanged (16 rounds); per-block fixed costs
//    (two 6-step shfl scans, dest table, tot/gb0 loads, stage barrier)
//    halve per element. Expert runs avg 128 elems = 512 B.
//  - LDS 74.3 KB -> 2 blocks/CU x 8 waves = 16 waves/CU: same 50%
//    residency as R12's 4x4 -- tile growth is occupancy-free.
//  - hist at 512 threads (16 ballot rounds/wave, es[16]).

#define TILE 8192          // elements per tile (512 threads, 8 waves)
#define WAVES 8
#define WCH  1024          // elements per wave
#define RND  16            // rounds of 64 per wave

__device__ __forceinline__ unsigned long long match_mask(
    unsigned key,
    unsigned long long b0, unsigned long long b1, unsigned long long b2,
    unsigned long long b3, unsigned long long b4, unsigned long long b5,
    unsigned long long am) {
  unsigned long long m = am;
  m &= (key & 1u)  ? b0 : ~b0;
  m &= (key & 2u)  ? b1 : ~b1;
  m &= (key & 4u)  ? b2 : ~b2;
  m &= (key & 8u)  ? b3 : ~b3;
  m &= (key & 16u) ? b4 : ~b4;
  m &= (key & 32u) ? b5 : ~b5;
  return m;
}

// Kernel 1: per-tile expert histogram via ballots (no atomics).
// countsT layout: [tile][64] -> one coalesced 256 B write per block.
__global__ __launch_bounds__(512) void hist_kernel(
    const int* __restrict__ idx, unsigned* __restrict__ countsT,
    int N, int nb) {
  __shared__ unsigned h[WAVES][64];
  const int wave = threadIdx.x >> 6;
  const int lane = threadIdx.x & 63;

  long long base = (long long)blockIdx.x * TILE;
  long long rem = (long long)N - base;
  unsigned cnt = 0;

  if (rem >= TILE) {
    const int4* v = (const int4*)(idx + base);
    unsigned es[16];
    #pragma unroll
    for (int k = 0; k < 4; ++k) {
      int4 x = v[threadIdx.x + k * 512];
      es[k * 4 + 0] = ((unsigned)x.x) & 63u;
      es[k * 4 + 1] = ((unsigned)x.y) & 63u;
      es[k * 4 + 2] = ((unsigned)x.z) & 63u;
      es[k * 4 + 3] = ((unsigned)x.w) & 63u;
    }
    #pragma unroll
    for (int r = 0; r < 16; ++r) {
      unsigned e = es[r];
      unsigned long long b0 = __ballot(e & 1u);
      unsigned long long b1 = __ballot(e & 2u);
      unsigned long long b2 = __ballot(e & 4u);
      unsigned long long b3 = __ballot(e & 8u);
      unsigned long long b4 = __ballot(e & 16u);
      unsigned long long b5 = __ballot(e & 32u);
      cnt += (unsigned)__popcll(
          match_mask((unsigned)lane, b0, b1, b2, b3, b4, b5, ~0ull));
    }
  } else {
    long long wstart = base + (long long)wave * WCH;
    for (int r = 0; r < RND; ++r) {
      long long i = wstart + (long long)r * 64 + lane;
      bool valid = i < (long long)N;
      unsigned long long am = __ballot(valid ? 1 : 0);
      unsigned e = valid ? (((unsigned)idx[i]) & 63u) : 0u;
      unsigned long long b0 = __ballot(e & 1u);
      unsigned long long b1 = __ballot(e & 2u);
      unsigned long long b2 = __ballot(e & 4u);
      unsigned long long b3 = __ballot(e & 8u);
      unsigned long long b4 = __ballot(e & 16u);
      unsigned long long b5 = __ballot(e & 32u);
      cnt += (unsigned)__popcll(
          match_mask((unsigned)lane, b0, b1, b2, b3, b4, b5, am));
    }
  }

  h[wave][lane] = cnt;
  __syncthreads();
  if (threadIdx.x < 64) {
    unsigned s = 0;
    #pragma unroll
    for (int w = 0; w < WAVES; ++w) s += h[w][threadIdx.x];
    countsT[(size_t)blockIdx.x * 64 + threadIdx.x] = s;
  }
}

// Kernel 2: per-expert exclusive scan over tiles, chunked through LDS.
// countsT[t*64+e]; strided accesses are L2-resident (256 KB total).
__global__ __launch_bounds__(256) void scan_kernel(
    unsigned* __restrict__ countsT, unsigned* __restrict__ totals,
    float* __restrict__ out_counts, int nb) {
  const int e = blockIdx.x;   // 0..63
  const int t = threadIdx.x;  // 0..255
  const int wave = t >> 6;
  const int lane = t & 63;

  __shared__ unsigned buf[2048];
  __shared__ unsigned wsum[4];

  unsigned carry = 0;
  for (int c = 0; c < nb; c += 2048) {
    int m = nb - c; if (m > 2048) m = 2048;
    for (int j = t; j < 2048; j += 256)
      buf[j] = (j < m) ? countsT[(size_t)(c + j) * 64 + e] : 0u;
    __syncthreads();
    unsigned v[8]; unsigned s = 0;
    #pragma unroll
    for (int k = 0; k < 8; ++k) { v[k] = buf[t * 8 + k]; s += v[k]; }
    unsigned inc = s;
    #pragma unroll
    for (int d = 1; d < 64; d <<= 1) {
      unsigned nv = __shfl_up(inc, d, 64);
      if (lane >= d) inc += nv;
    }
    if (lane == 63) wsum[wave] = inc;
    __syncthreads();
    unsigned woff = 0;
    for (int w = 0; w < wave; ++w) woff += wsum[w];
    unsigned btot = wsum[0] + wsum[1] + wsum[2] + wsum[3];
    unsigned run = carry + woff + (inc - s);
    #pragma unroll
    for (int k = 0; k < 8; ++k) { buf[t * 8 + k] = run; run += v[k]; }
    __syncthreads();
    for (int j = t; j < 2048; j += 256)
      if (j < m) countsT[(size_t)(c + j) * 64 + e] = buf[j];
    carry += btot;
    __syncthreads();
  }
  if (t == 0) {
    totals[e] = carry;
    out_counts[e] = (float)carry;  // output 2
  }
}

// Kernel 3: LDS-staged ballot sort, leader-publish counts, coalesced writes.
__global__ __launch_bounds__(512, 4) void scatter_kernel(
    const int* __restrict__ idx, const float* __restrict__ scores,
    const unsigned* __restrict__ baseT, const unsigned* __restrict__ totals,
    float* __restrict__ out_scores, float* __restrict__ out_idx,
    int N, int nb) {
  // 16-byte aligned: accessed via int4/uint4 casts (ds_*_b128).
  __shared__ __align__(16) uint2 sdat[TILE];                  // 64 KB; first 32 KB alias idx staging
  __shared__ __align__(16) unsigned char tmpb[WAVES][64][RND];// 8 KB leader-publish transpose
  __shared__ unsigned shc[WAVES][64];                         // per-wave per-expert totals
  __shared__ unsigned gdest[64];                              // global dest = gdest[e] + lds_pos

  const int t = threadIdx.x;
  const int wave = t >> 6;
  const int lane = t & 63;
  const unsigned long long lt = (1ull << lane) - 1ull;

  const long long base = (long long)blockIdx.x * TILE;
  const long long start = base + (long long)wave * WCH;
  const bool fullt = (base + TILE) <= (long long)N;

  // hoisted global loads (consumed at table-calc time)
  const unsigned tot = totals[lane];
  const unsigned gb0 = baseT[(size_t)blockIdx.x * 64 + lane];  // coalesced

  unsigned e_pk[4] = {0, 0, 0, 0};
  unsigned r_pk[4] = {0, 0, 0, 0};
  float    sreg[RND];
  unsigned c_pk[4];
  unsigned wtotal = 0;

  unsigned* idxs = (unsigned*)sdat;  // idx staging aliases sdat (pass-1 only)

  if (fullt) {
    // ---- Stage: all global loads up front; idx -> LDS via b128 ----
    {
      const int4* gi = (const int4*)(idx + base);
      int4 a0 = gi[t];
      int4 a1 = gi[t + 512];
      int4 a2 = gi[t + 1024];
      int4 a3 = gi[t + 1536];
      #pragma unroll
      for (int r = 0; r < RND; ++r) sreg[r] = scores[start + r * 64 + lane];
      ((int4*)idxs)[t] = a0;
      ((int4*)idxs)[t + 512] = a1;
      ((int4*)idxs)[t + 1024] = a2;
      ((int4*)idxs)[t + 1536] = a3;
    }
    // zero my tmp row (same-wave DS ordering vs publishes)
    *(uint4*)(&tmpb[wave][lane][0]) = make_uint4(0u, 0u, 0u, 0u);
    __syncthreads();

    // ---- Pass 1: ballots from LDS; leader publishes per-round count ----
    #pragma unroll
    for (int r = 0; r < RND; ++r) {
      unsigned e = idxs[wave * WCH + r * 64 + lane] & 63u;
      unsigned long long b0 = __ballot(e & 1u);
      unsigned long long b1 = __ballot(e & 2u);
      unsigned long long b2 = __ballot(e & 4u);
      unsigned long long b3 = __ballot(e & 8u);
      unsigned long long b4 = __ballot(e & 16u);
      unsigned long long b5 = __ballot(e & 32u);
      unsigned long long ms = match_mask(e, b0, b1, b2, b3, b4, b5, ~0ull);
      unsigned rank = (unsigned)__popcll(ms & lt);
      unsigned rcnt = (unsigned)__popcll(ms);
      if (rank == 0) tmpb[wave][e][r] = (unsigned char)rcnt;
      const int q = r >> 2, sh = (r & 3) * 8;
      e_pk[q] |= e << sh;
      r_pk[q] |= rank << sh;
    }
    uint4 cw = *(const uint4*)(&tmpb[wave][lane][0]);  // after publishes (in-order)
    c_pk[0] = cw.x; c_pk[1] = cw.y; c_pk[2] = cw.z; c_pk[3] = cw.w;
  } else {
    for (int j = t; j < TILE; j += 512) sdat[j].y = 0xFFFFFFFFu;
    *(uint4*)(&tmpb[wave][lane][0]) = make_uint4(0u, 0u, 0u, 0u);
    __syncthreads();
    for (int r = 0; r < RND; ++r) {
      long long i = start + (long long)r * 64 + lane;
      bool valid = i < (long long)N;
      unsigned long long am = __ballot(valid ? 1 : 0);
      unsigned e = valid ? (((unsigned)idx[i]) & 63u) : 0u;
      sreg[r] = valid ? scores[i] : 0.0f;
      unsigned long long b0 = __ballot(e & 1u);
      unsigned long long b1 = __ballot(e & 2u);
      unsigned long long b2 = __ballot(e & 4u);
      unsigned long long b3 = __ballot(e & 8u);
      unsigned long long b4 = __ballot(e & 16u);
      unsigned long long b5 = __ballot(e & 32u);
      unsigned long long ms = match_mask(e, b0, b1, b2, b3, b4, b5, am);
      unsigned rank = (unsigned)__popcll(ms & lt);
      unsigned rcnt = (unsigned)__popcll(ms);
      if (valid && rank == 0) tmpb[wave][e][r] = (unsigned char)rcnt;
      const int q = r >> 2, sh = (r & 3) * 8;
      e_pk[q] |= e << sh;
      r_pk[q] |= rank << sh;
    }
    uint4 cw = *(const uint4*)(&tmpb[wave][lane][0]);
    c_pk[0] = cw.x; c_pk[1] = cw.y; c_pk[2] = cw.z; c_pk[3] = cw.w;
  }

  // wave total for expert==lane = byte-sum of c_pk (SIMD-in-register)
  {
    unsigned acc = 0;
    #pragma unroll
    for (int q = 0; q < 4; ++q)
      acc += (c_pk[q] & 0x00FF00FFu) + ((c_pk[q] >> 8) & 0x00FF00FFu);
    wtotal = (acc & 0xFFFFu) + (acc >> 16);
  }

  shc[wave][lane] = wtotal;
  __syncthreads();

  // ---- Block-level geometry for expert == lane ----
  unsigned cw_[WAVES];
  unsigned bt = 0;
  #pragma unroll
  for (int w = 0; w < WAVES; ++w) { cw_[w] = shc[w][lane]; bt += cw_[w]; }
  unsigned wpre = 0;                        // waves before me, same expert
  #pragma unroll
  for (int w = 0; w < WAVES; ++w) if (w < wave) wpre += cw_[w];

  // exclusive scan of block totals over experts -> block-grouped LDS start
  unsigned s = bt;
  #pragma unroll
  for (int d = 1; d < 64; d <<= 1) {
    unsigned nv = __shfl_up(s, d, 64);
    if (lane >= d) s += nv;
  }
  unsigned bstart = s - bt;
  unsigned wbase = bstart + wpre;           // this wave's start for expert==lane

  // per-round cursors (register prefix)
  unsigned cur[RND];
  {
    unsigned acc = wbase;
    #pragma unroll
    for (int r = 0; r < RND; ++r) {
      cur[r] = acc;
      acc += (c_pk[r >> 2] >> ((r & 3) * 8)) & 0xffu;
    }
  }

  // global dest table (identical in all waves; wave 0 writes)
  if (wave == 0) {
    unsigned s2 = tot;
    #pragma unroll
    for (int d = 1; d < 64; d <<= 1) {
      unsigned nv = __shfl_up(s2, d, 64);
      if (lane >= d) s2 += nv;
    }
    unsigned estart = s2 - tot;             // global start of expert==lane
    gdest[lane] = estart + gb0 - bstart;    // u32 wraparound ok
  }

  // ---- Pass 2: scatter into block-grouped LDS (reg -> ds_write_b64) ----
  if (fullt) {
    #pragma unroll
    for (int r = 0; r < RND; ++r) {
      unsigned i32 = (unsigned)start + r * 64 + lane;
      const int q = r >> 2, sh = (r & 3) * 8;
      unsigned e    = (e_pk[q] >> sh) & 0xffu;
      unsigned rank = (r_pk[q] >> sh) & 0xffu;
      unsigned pos = (unsigned)__shfl((int)cur[r], (int)e, 64) + rank;
      sdat[pos] = make_uint2(__float_as_uint(sreg[r]), (i32 << 6) | e);
    }
  } else {
    for (int r = 0; r < RND; ++r) {
      long long i = start + (long long)r * 64 + lane;
      bool valid = i < (long long)N;
      const int q = r >> 2, sh = (r & 3) * 8;
      unsigned e    = (e_pk[q] >> sh) & 0xffu;
      unsigned rank = (r_pk[q] >> sh) & 0xffu;
      unsigned pos = (unsigned)__shfl((int)cur[r], (int)e, 64) + rank;
      if (valid) {
        sdat[pos] = make_uint2(__float_as_uint(sreg[r]), (((unsigned)i) << 6) | e);
      }
    }
  }
  __syncthreads();

  // ---- Phase D: coalesced write-out (runs avg 128 elements = 512 B) ----
  if (fullt) {
    #pragma unroll
    for (int k = 0; k < TILE / 512; ++k) {
      int j = t + k * 512;
      uint2 v = sdat[j];
      unsigned e = v.y & 63u;
      unsigned d = gdest[e] + (unsigned)j;
      out_scores[d] = __uint_as_float(v.x);
      out_idx[d] = (float)(v.y >> 6);
    }
  } else {
    for (int j = t; j < TILE; j += 512) {
      uint2 v = sdat[j];
      if (v.y == 0xFFFFFFFFu) continue;
      unsigned e = v.y & 63u;
      unsigned d = gdest[e] + (unsigned)j;
      out_scores[d] = __uint_as_float(v.x);
      out_idx[d] = (float)(v.y >> 6);
    }
  }
}

extern "C" void kernel_launch(void* const* d_in, const int* in_sizes, int n_in,
                              void* d_out, int out_size, void* d_ws, size_t ws_size,
                              hipStream_t stream) {
  const float* scores = (const float*)d_in[0];
  const int* idx = (const int*)d_in[1];
  int N = in_sizes[0];  // 8388608

  float* out_scores = (float*)d_out;
  float* out_idx = out_scores + N;
  float* out_counts = out_idx + N;

  int nb = (N + TILE - 1) / TILE;                 // 1024
  unsigned* countsT = (unsigned*)d_ws;            // [nb][64], scanned in place
  unsigned* totals = countsT + (size_t)nb * 64;   // [64]

  hist_kernel<<<nb, 512, 0, stream>>>(idx, countsT, N, nb);
  scan_kernel<<<64, 256, 0, stream>>>(countsT, totals, out_counts, nb);
  scatter_kernel<<<nb, 512, 0, stream>>>(idx, scores, countsT, totals,
                                         out_scores, out_idx, N, nb);
}